// Round 9
// baseline (284.710 us; speedup 1.0000x reference)
//
#include <hip/hip_runtime.h>

typedef unsigned short ushort_t;
typedef __attribute__((ext_vector_type(8))) short short8;
typedef __attribute__((ext_vector_type(4))) float f32x4;

#define BT 4096
#define TSEQ 2048
#define CC 1024
#define NH 16
#define DH 64
#define HID 4096
#define ATT_SCALE 0.03125f   /* C^-0.5 = 1/32 (reference scales by C, not DH) */

__device__ __forceinline__ ushort_t f2bf(float f) {
    unsigned u = __float_as_uint(f);
    u = u + 0x7fffu + ((u >> 16) & 1u);
    return (ushort_t)(u >> 16);
}

typedef const __attribute__((address_space(1))) unsigned int* gptr_t;
typedef __attribute__((address_space(3))) unsigned int* lptr_t;
__device__ __forceinline__ void gload_lds16(const void* g, void* l) {
    __builtin_amdgcn_global_load_lds((gptr_t)g, (lptr_t)l, 16, 0, 0);
}

// ---------------------------------------------------------------------------
// Tiled transpose + f32->bf16 convert:  in [R][Cn] f32  ->  out [Cn][R] bf16
// ---------------------------------------------------------------------------
__global__ __launch_bounds__(256) void transpose_cvt(
    const float* __restrict__ in, ushort_t* __restrict__ out, int R, int Cn)
{
    __shared__ float tile[32][33];
    size_t off = (size_t)blockIdx.z * R * Cn;
    int c0 = blockIdx.x * 32, r0 = blockIdx.y * 32;
    int tx = threadIdx.x & 31, ty = threadIdx.x >> 5;
#pragma unroll
    for (int q = 0; q < 4; ++q)
        tile[ty + 8 * q][tx] = in[off + (size_t)(r0 + ty + 8 * q) * Cn + c0 + tx];
    __syncthreads();
#pragma unroll
    for (int q = 0; q < 4; ++q)
        out[off + (size_t)(c0 + ty + 8 * q) * R + r0 + tx] = f2bf(tile[tx][ty + 8 * q]);
}

// ---------------------------------------------------------------------------
// LayerNorm row kernel: x f32 [rows][1024] -> out bf16.
// ---------------------------------------------------------------------------
__global__ __launch_bounds__(256) void ln_kernel(
    const float* __restrict__ x, const float* __restrict__ g,
    const float* __restrict__ b, ushort_t* __restrict__ out)
{
    int row = blockIdx.x;
    const float4 xv = ((const float4*)(x + (size_t)row * CC))[threadIdx.x];
    float s = xv.x + xv.y + xv.z + xv.w;
    float s2 = xv.x * xv.x + xv.y * xv.y + xv.z * xv.z + xv.w * xv.w;
#pragma unroll
    for (int d = 1; d < 64; d <<= 1) {
        s += __shfl_xor(s, d);
        s2 += __shfl_xor(s2, d);
    }
    __shared__ float ps[4], ps2[4];
    int w = threadIdx.x >> 6, lane = threadIdx.x & 63;
    if (lane == 0) { ps[w] = s; ps2[w] = s2; }
    __syncthreads();
    s = ps[0] + ps[1] + ps[2] + ps[3];
    s2 = ps2[0] + ps2[1] + ps2[2] + ps2[3];
    float mu = s * (1.0f / CC);
    float var = s2 * (1.0f / CC) - mu * mu;
    float rs = rsqrtf(var + 1e-5f);
    int c = threadIdx.x * 4;
    const float4 gv = ((const float4*)g)[threadIdx.x];
    const float4 bv = ((const float4*)b)[threadIdx.x];
    ushort_t u0 = f2bf((xv.x - mu) * rs * gv.x + bv.x);
    ushort_t u1 = f2bf((xv.y - mu) * rs * gv.y + bv.y);
    ushort_t u2 = f2bf((xv.z - mu) * rs * gv.z + bv.z);
    ushort_t u3 = f2bf((xv.w - mu) * rs * gv.w + bv.w);
    unsigned lo = (unsigned)u0 | ((unsigned)u1 << 16);
    unsigned hi = (unsigned)u2 | ((unsigned)u3 << 16);
    ((uint2*)(out + (size_t)row * CC + c))[0] = make_uint2(lo, hi);
}

// ---------------------------------------------------------------------------
// LDS-staged NT GEMM (m97 structure): BMxBN tile, BK=32, 256 threads.
// A row stride = lda, Bt row stride = ldb (elements).
// MODE 0: f32 out = acc + bias[n] + resid[m][n]
// MODE 1: bf16 out = relu(acc + bias[n])
// MODE 2: QKV scatter (Q prescaled by ATT_SCALE)
// MODE 3: split-K partial: f32 out at plane blockIdx.z (A/B column offset z*K)
// ---------------------------------------------------------------------------
template <int BM, int BN, int WM, int WN, int MR, int NR, int MODE>
__global__ __launch_bounds__(256) void gemm_tile(
    const ushort_t* __restrict__ A, const ushort_t* __restrict__ Bt,
    int N, int K, int lda, int ldb,
    const float* __restrict__ bias, const float* __restrict__ resid,
    void* __restrict__ out0, void* __restrict__ out1, void* __restrict__ out2)
{
    static_assert(WM * WN == 4 && WM * MR * 16 == BM && WN * NR * 16 == BN, "geom");
    __shared__ ushort_t As[BM * 32];
    __shared__ ushort_t Bs[BN * 32];

    const int t = threadIdx.x;
    const int w = t >> 6, lane = t & 63, g = lane >> 4, c = lane & 15;
    const int wr = w / WN, wc = w % WN;
    const int m0 = blockIdx.x * BM;
    const int n0 = blockIdx.y * BN;
    if (MODE == 3) {   // K-chunk column offset
        A += (size_t)blockIdx.z * K;
        Bt += (size_t)blockIdx.z * K;
    }

    f32x4 acc[MR][NR];
#pragma unroll
    for (int mi = 0; mi < MR; ++mi)
#pragma unroll
        for (int ni = 0; ni < NR; ++ni) acc[mi][ni] = f32x4{0.f, 0.f, 0.f, 0.f};

    const ushort_t* Ard = As + (size_t)(wr * MR * 16 + c) * 32 + g * 8;
    const ushort_t* Brd = Bs + (size_t)(wc * NR * 16 + c) * 32 + g * 8;
    const int arow = t >> 2, acol = (t & 3) * 8;

    for (int k0 = 0; k0 < K; k0 += 32) {
        __syncthreads();
#pragma unroll
        for (int j = 0; j < BM / 64; ++j)
            gload_lds16(A + (size_t)(m0 + j * 64 + arow) * lda + k0 + acol,
                        As + (size_t)j * 2048 + t * 8);
#pragma unroll
        for (int j = 0; j < BN / 64; ++j)
            gload_lds16(Bt + (size_t)(n0 + j * 64 + arow) * ldb + k0 + acol,
                        Bs + (size_t)j * 2048 + t * 8);
        __syncthreads();

        short8 af[MR], bf[NR];
#pragma unroll
        for (int mi = 0; mi < MR; ++mi) af[mi] = *(const short8*)(Ard + mi * 512);
#pragma unroll
        for (int ni = 0; ni < NR; ++ni) bf[ni] = *(const short8*)(Brd + ni * 512);
#pragma unroll
        for (int mi = 0; mi < MR; ++mi)
#pragma unroll
            for (int ni = 0; ni < NR; ++ni)
                acc[mi][ni] = __builtin_amdgcn_mfma_f32_16x16x32_bf16(
                    af[mi], bf[ni], acc[mi][ni], 0, 0, 0);
    }

#pragma unroll
    for (int mi = 0; mi < MR; ++mi)
#pragma unroll
        for (int ni = 0; ni < NR; ++ni)
#pragma unroll
            for (int i = 0; i < 4; ++i) {
                int row = m0 + wr * MR * 16 + mi * 16 + g * 4 + i;
                int col = n0 + wc * NR * 16 + ni * 16 + c;
                float v = acc[mi][ni][i];
                if (MODE == 0) {
                    v += bias[col] + resid[(size_t)row * N + col];
                    ((float*)out0)[(size_t)row * N + col] = v;
                } else if (MODE == 1) {
                    v += bias[col];
                    v = v > 0.f ? v : 0.f;
                    ((ushort_t*)out0)[(size_t)row * N + col] = f2bf(v);
                } else if (MODE == 3) {
                    ((float*)out0)[(size_t)blockIdx.z * BT * N + (size_t)row * N + col] = v;
                } else {
                    int bb = row >> 11, tt = row & (TSEQ - 1);
                    if (col < 1024) {
                        int head = col >> 6, d = col & 63;
                        ((ushort_t*)out0)[((size_t)(bb * NH + head) * TSEQ + tt) * DH + d] =
                            f2bf(v * ATT_SCALE);
                    } else if (col < 2048) {
                        int head = (col - 1024) >> 6, d = col & 63;
                        ((ushort_t*)out1)[((size_t)(bb * NH + head) * TSEQ + tt) * DH + d] = f2bf(v);
                    } else {
                        int head = (col - 2048) >> 6, d = col & 63;
                        ((ushort_t*)out2)[((size_t)(bb * NH + head) * DH + d) * TSEQ + tt] = f2bf(v);
                    }
                }
            }
}

// ---------------------------------------------------------------------------
// FFN2 combine: out[m][n] = sum_z parts[z][m][n] + bias[n] + resid[m][n]
// grid 4096 x 256 threads; one float4 per thread.
// ---------------------------------------------------------------------------
__global__ __launch_bounds__(256) void ffn2_combine(
    const float* __restrict__ parts, const float* __restrict__ bias,
    const float* __restrict__ resid, float* __restrict__ out)
{
    const size_t idx = (size_t)blockIdx.x * 256 + threadIdx.x;   // float4 index
    const size_t off = idx * 4;
    const size_t m = off >> 10, col = off & 1023;
    float4 a0 = ((const float4*)(parts + (size_t)0 * BT * CC + off))[0];
    float4 a1 = ((const float4*)(parts + (size_t)1 * BT * CC + off))[0];
    float4 a2 = ((const float4*)(parts + (size_t)2 * BT * CC + off))[0];
    float4 a3 = ((const float4*)(parts + (size_t)3 * BT * CC + off))[0];
    float4 bv = ((const float4*)(bias + col))[0];
    float4 rv = ((const float4*)(resid + off))[0];
    float4 o;
    o.x = a0.x + a1.x + a2.x + a3.x + bv.x + rv.x;
    o.y = a0.y + a1.y + a2.y + a3.y + bv.y + rv.y;
    o.z = a0.z + a1.z + a2.z + a3.z + bv.z + rv.z;
    o.w = a0.w + a1.w + a2.w + a3.w + bv.w + rv.w;
    ((float4*)(out + off))[0] = o;
    (void)m;
}

// ===========================================================================
// Flash machinery for the FALLBACK kernel only (register version).
// ===========================================================================
#define FLASH_BODY(st, kc, kn, PREF_COND, MASK_COND)                               \
    {                                                                              \
        const int S0 = (st) * 64;                                                  \
        short8 vv[4][2];                                                           \
        _Pragma("unroll") for (int nf = 0; nf < 4; ++nf)                           \
            _Pragma("unroll") for (int ks = 0; ks < 2; ++ks)                       \
                vv[nf][ks] = *(const short8*)(vp + (size_t)(nf * 16 + c) * TSEQ +  \
                                              S0 + ks * 32 + g * 8);               \
        if (PREF_COND) {                                                           \
            _Pragma("unroll") for (int sub = 0; sub < 4; ++sub)                    \
                _Pragma("unroll") for (int ks = 0; ks < 2; ++ks)                   \
                    kn[sub][ks] = *(const short8*)(kp +                            \
                        (size_t)(S0 + 64 + 16 * sub + c) * DH + ks * 32 + g * 8);  \
        }                                                                          \
        f32x4 sa[4];                                                               \
        _Pragma("unroll") for (int sub = 0; sub < 4; ++sub) {                      \
            f32x4 t0 = f32x4{0.f, 0.f, 0.f, 0.f};                                  \
            t0 = __builtin_amdgcn_mfma_f32_16x16x32_bf16(kc[sub][0], bq0, t0, 0, 0, 0); \
            t0 = __builtin_amdgcn_mfma_f32_16x16x32_bf16(kc[sub][1], bq1, t0, 0, 0, 0); \
            sa[sub] = t0;                                                          \
        }                                                                          \
        float pvv[16];                                                             \
        _Pragma("unroll") for (int sub = 0; sub < 4; ++sub)                        \
            _Pragma("unroll") for (int i = 0; i < 4; ++i) pvv[4 * sub + i] = sa[sub][i]; \
        if (MASK_COND) {                                                           \
            _Pragma("unroll") for (int sub = 0; sub < 4; ++sub)                    \
                _Pragma("unroll") for (int i = 0; i < 4; ++i)                      \
                    if (S0 + 16 * sub + 4 * g + i > q0 + c) pvv[4 * sub + i] = -INFINITY; \
        }                                                                          \
        float tmax = pvv[0];                                                       \
        _Pragma("unroll") for (int j = 1; j < 16; ++j) tmax = fmaxf(tmax, pvv[j]); \
        tmax = fmaxf(tmax, __shfl_xor(tmax, 16));                                  \
        tmax = fmaxf(tmax, __shfl_xor(tmax, 32));                                  \
        if (!__all(tmax - m_ <= 8.0f)) {                                           \
            float mn = fmaxf(m_, tmax);                                            \
            float fac = __expf(m_ - mn);                                           \
            m_ = mn;                                                               \
            l_ *= fac;                                                             \
            _Pragma("unroll") for (int i = 0; i < 4; ++i) {                        \
                float fr = __shfl(fac, 4 * g + i);                                 \
                _Pragma("unroll") for (int nf = 0; nf < 4; ++nf) o[nf][i] *= fr;   \
            }                                                                      \
        }                                                                          \
        float pp[16], rs = 0.f;                                                    \
        _Pragma("unroll") for (int j = 0; j < 16; ++j) {                           \
            pp[j] = __expf(pvv[j] - m_); rs += pp[j];                              \
        }                                                                          \
        rs += __shfl_xor(rs, 16);                                                  \
        rs += __shfl_xor(rs, 32);                                                  \
        l_ += rs;                                                                  \
        _Pragma("unroll") for (int sub = 0; sub < 4; ++sub) {                      \
            unsigned lo = (__float_as_uint(pp[4 * sub + 0]) >> 16) |               \
                          (__float_as_uint(pp[4 * sub + 1]) & 0xffff0000u);        \
            unsigned hi = (__float_as_uint(pp[4 * sub + 2]) >> 16) |               \
                          (__float_as_uint(pp[4 * sub + 3]) & 0xffff0000u);        \
            *(uint2*)(pw + 16 * sub + 4 * g) = make_uint2(lo, hi);                 \
        }                                                                          \
        asm volatile("s_waitcnt lgkmcnt(0)" ::: "memory");                         \
        short8 pa0 = *(const short8*)(&Plds[w][c * 72 + g * 8]);                   \
        short8 pa1 = *(const short8*)(&Plds[w][c * 72 + 32 + g * 8]);              \
        _Pragma("unroll") for (int nf = 0; nf < 4; ++nf) {                         \
            o[nf] = __builtin_amdgcn_mfma_f32_16x16x32_bf16(pa0, vv[nf][0], o[nf], 0, 0, 0); \
            o[nf] = __builtin_amdgcn_mfma_f32_16x16x32_bf16(pa1, vv[nf][1], o[nf], 0, 0, 0); \
        }                                                                          \
    }

// ---------------------------------------------------------------------------
// Fallback: full-depth flash (register version).  grid (B*H, T/64), block 256.
// ---------------------------------------------------------------------------
__global__ __launch_bounds__(256) void flash_attn(
    const ushort_t* __restrict__ Q, const ushort_t* __restrict__ Kb,
    const ushort_t* __restrict__ Vt, ushort_t* __restrict__ attout)
{
    __shared__ ushort_t Plds[4][16 * 72];
    const int w = threadIdx.x >> 6, lane = threadIdx.x & 63;
    const int g = lane >> 4, c = lane & 15;
    const int bh = blockIdx.x, bb = bh >> 4, hh = bh & 15;
    const int q0 = blockIdx.y * 64 + w * 16;
    const ushort_t* qp = Q + (size_t)bh * TSEQ * DH;
    const ushort_t* kp = Kb + (size_t)bh * TSEQ * DH;
    const ushort_t* vp = Vt + (size_t)bh * DH * TSEQ;

    const short8 bq0 = *(const short8*)(qp + (size_t)(q0 + c) * DH + g * 8);
    const short8 bq1 = *(const short8*)(qp + (size_t)(q0 + c) * DH + 32 + g * 8);

    float m_ = -INFINITY, l_ = 0.f;
    f32x4 o[4];
#pragma unroll
    for (int nf = 0; nf < 4; ++nf) o[nf] = f32x4{0.f, 0.f, 0.f, 0.f};

    const int nst = q0 / 64 + 1;
    ushort_t* pw = &Plds[w][c * 72];

    short8 kkA[4][2], kkB[4][2];
#pragma unroll
    for (int sub = 0; sub < 4; ++sub)
#pragma unroll
        for (int ks = 0; ks < 2; ++ks)
            kkA[sub][ks] = *(const short8*)(kp + (size_t)(16 * sub + c) * DH + ks * 32 + g * 8);

    for (int st = 0; st < nst; st += 2) {
        FLASH_BODY(st, kkA, kkB, (st + 1 < nst), (st == nst - 1));
        if (st + 1 < nst) {
            const int st1 = st + 1;
            FLASH_BODY(st1, kkB, kkA, (st1 + 1 < nst), (st1 == nst - 1));
        }
    }

#pragma unroll
    for (int i = 0; i < 4; ++i) {
        float rl = 1.0f / __shfl(l_, 4 * g + i);
        int tt = q0 + 4 * g + i;
#pragma unroll
        for (int nf = 0; nf < 4; ++nf)
            attout[((size_t)(bb * TSEQ + tt)) * CC + hh * DH + nf * 16 + c] =
                f2bf(o[nf][i] * rl);
    }
}

// ---------------------------------------------------------------------------
// Split flash v2: K/V tiles staged ONCE per block into LDS (global_load_lds,
// inverse-swizzled global source, byte ^= (row&7)<<4), shared by all 4 waves.
// grid (B*H, T/64, 4 s-chunks of 8 tiles), block 256.
// ---------------------------------------------------------------------------
__global__ __launch_bounds__(256) void flash_split(
    const ushort_t* __restrict__ Q, const ushort_t* __restrict__ Kb,
    const ushort_t* __restrict__ Vt, float* __restrict__ opart,
    float* __restrict__ mlpart, ushort_t* __restrict__ attout)
{
    __shared__ ushort_t Ks[64 * 64];        // [s_loc][d], rows 128 B, swizzled
    __shared__ ushort_t Vs[64 * 64];        // [d][s_loc], rows 128 B, swizzled
    __shared__ ushort_t Plds[4][16 * 72];
    const int t = threadIdx.x;
    const int w = t >> 6, lane = t & 63;
    const int g = lane >> 4, c = lane & 15;
    const int bh = blockIdx.x, qb = blockIdx.y, sc = blockIdx.z;
    if (sc * 8 > qb) return;                // beyond causal bound
    const int bb = bh >> 4, hh = bh & 15;
    const int q0 = qb * 64 + w * 16;
    const ushort_t* qp = Q + (size_t)bh * TSEQ * DH;
    const char* kpB = (const char*)(Kb + (size_t)bh * TSEQ * DH);
    const char* vpB = (const char*)(Vt + (size_t)bh * DH * TSEQ);

    const short8 bq0 = *(const short8*)(qp + (size_t)(q0 + c) * DH + g * 8);
    const short8 bq1 = *(const short8*)(qp + (size_t)(q0 + c) * DH + 32 + g * 8);

    float m_ = -INFINITY, l_ = 0.f;
    f32x4 o[4];
#pragma unroll
    for (int nf = 0; nf < 4; ++nf) o[nf] = f32x4{0.f, 0.f, 0.f, 0.f};

    const int st0 = sc * 8;
    const int send = (st0 + 7 < qb) ? st0 + 7 : qb;
    ushort_t* pw = &Plds[w][c * 72];
    const unsigned bxor = (unsigned)((c & 7) << 4);   // read-side swizzle

    const int srow = t >> 3, sb = (t & 7) * 16;
#define STAGE_KV(ST)                                                                \
    {                                                                               \
        const int S0_ = (ST) * 64;                                                  \
        _Pragma("unroll") for (int j = 0; j < 2; ++j) {                             \
            int r = j * 32 + srow;                                                  \
            int bs = sb ^ ((r & 7) << 4);                                           \
            gload_lds16(kpB + (size_t)(S0_ + r) * 128 + bs,                         \
                        (char*)Ks + r * 128 + sb);                                  \
            gload_lds16(vpB + (size_t)r * (TSEQ * 2) + S0_ * 2 + bs,                \
                        (char*)Vs + r * 128 + sb);                                  \
        }                                                                           \
    }

    STAGE_KV(st0);
    for (int st = st0; st <= send; ++st) {
        const int S0 = st * 64;
        __syncthreads();   // staged data visible (drains vmcnt)

        __builtin_amdgcn_s_setprio(1);
        f32x4 sa[4];
#pragma unroll
        for (int sub = 0; sub < 4; ++sub) {
            const char* kr = (const char*)Ks + (16 * sub + c) * 128;
            short8 k0 = *(const short8*)(kr + ((g * 16) ^ bxor));
            short8 k1 = *(const short8*)(kr + ((64 + g * 16) ^ bxor));
            f32x4 t0 = f32x4{0.f, 0.f, 0.f, 0.f};
            t0 = __builtin_amdgcn_mfma_f32_16x16x32_bf16(k0, bq0, t0, 0, 0, 0);
            t0 = __builtin_amdgcn_mfma_f32_16x16x32_bf16(k1, bq1, t0, 0, 0, 0);
            sa[sub] = t0;
        }
        __builtin_amdgcn_s_setprio(0);

        float pvv[16];
#pragma unroll
        for (int sub = 0; sub < 4; ++sub)
#pragma unroll
            for (int i = 0; i < 4; ++i) pvv[4 * sub + i] = sa[sub][i];
        if (st == qb) {   // diagonal tile
#pragma unroll
            for (int sub = 0; sub < 4; ++sub)
#pragma unroll
                for (int i = 0; i < 4; ++i)
                    if (S0 + 16 * sub + 4 * g + i > q0 + c) pvv[4 * sub + i] = -INFINITY;
        }
        float tmax = pvv[0];
#pragma unroll
        for (int j = 1; j < 16; ++j) tmax = fmaxf(tmax, pvv[j]);
        tmax = fmaxf(tmax, __shfl_xor(tmax, 16));
        tmax = fmaxf(tmax, __shfl_xor(tmax, 32));
        if (!__all(tmax - m_ <= 8.0f)) {   // defer-max
            float mn = fmaxf(m_, tmax);
            float fac = __expf(m_ - mn);
            m_ = mn;
            l_ *= fac;
#pragma unroll
            for (int i = 0; i < 4; ++i) {
                float fr = __shfl(fac, 4 * g + i);
#pragma unroll
                for (int nf = 0; nf < 4; ++nf) o[nf][i] *= fr;
            }
        }
        float pp[16], rs = 0.f;
#pragma unroll
        for (int j = 0; j < 16; ++j) { pp[j] = __expf(pvv[j] - m_); rs += pp[j]; }
        rs += __shfl_xor(rs, 16);
        rs += __shfl_xor(rs, 32);
        l_ += rs;

        // P -> bf16 (truncate), LDS transpose: row q=c gets s_local 16sub+4g+i
#pragma unroll
        for (int sub = 0; sub < 4; ++sub) {
            unsigned lo = (__float_as_uint(pp[4 * sub + 0]) >> 16) |
                          (__float_as_uint(pp[4 * sub + 1]) & 0xffff0000u);
            unsigned hi = (__float_as_uint(pp[4 * sub + 2]) >> 16) |
                          (__float_as_uint(pp[4 * sub + 3]) & 0xffff0000u);
            *(uint2*)(pw + 16 * sub + 4 * g) = make_uint2(lo, hi);
        }
        asm volatile("s_waitcnt lgkmcnt(0)" ::: "memory");
        short8 pa0 = *(const short8*)(&Plds[w][c * 72 + g * 8]);
        short8 pa1 = *(const short8*)(&Plds[w][c * 72 + 32 + g * 8]);

        __builtin_amdgcn_s_setprio(1);
#pragma unroll
        for (int nf = 0; nf < 4; ++nf) {
            const char* vr = (const char*)Vs + (nf * 16 + c) * 128;
            short8 v0 = *(const short8*)(vr + ((g * 16) ^ bxor));
            short8 v1 = *(const short8*)(vr + ((64 + g * 16) ^ bxor));
            o[nf] = __builtin_amdgcn_mfma_f32_16x16x32_bf16(pa0, v0, o[nf], 0, 0, 0);
            o[nf] = __builtin_amdgcn_mfma_f32_16x16x32_bf16(pa1, v1, o[nf], 0, 0, 0);
        }
        __builtin_amdgcn_s_setprio(0);

        __syncthreads();   // all LDS reads done before restage
        if (st < send) STAGE_KV(st + 1);
    }
#undef STAGE_KV

    if (qb < 8) {   // single chunk: finalize directly
#pragma unroll
        for (int i = 0; i < 4; ++i) {
            float rl = 1.0f / __shfl(l_, 4 * g + i);
            int tt = q0 + 4 * g + i;
#pragma unroll
            for (int nf = 0; nf < 4; ++nf)
                attout[((size_t)(bb * TSEQ + tt)) * CC + hh * DH + nf * 16 + c] =
                    f2bf(o[nf][i] * rl);
        }
    } else {
        const size_t slot = (size_t)(bh * 32 + qb) * 4 + sc;
        float* op = opart + slot * 4096;
#pragma unroll
        for (int nf = 0; nf < 4; ++nf)
#pragma unroll
            for (int i = 0; i < 4; ++i)
                op[(size_t)(w * 16 + 4 * g + i) * 64 + nf * 16 + c] = o[nf][i];
        if (g == 0) {
            mlpart[slot * 128 + w * 16 + c] = m_;
            mlpart[slot * 128 + 64 + w * 16 + c] = l_;
        }
    }
}

// ---------------------------------------------------------------------------
// Combine partials for qb >= 8.  grid (B*H, 24) -> qb = blockIdx.y + 8.
// ---------------------------------------------------------------------------
__global__ __launch_bounds__(256) void flash_combine(
    const float* __restrict__ opart, const float* __restrict__ mlpart,
    ushort_t* __restrict__ attout)
{
    const int bh = blockIdx.x, qb = blockIdx.y + 8;
    const int bb = bh >> 4, hh = bh & 15;
    const int nsc = (qb >> 3) + 1;      // 2..4
    const int t = threadIdx.x, r = t >> 2, qc = t & 3;
    const size_t slot0 = (size_t)(bh * 32 + qb) * 4;

    float mi[4], li[4];
    float M = -INFINITY;
#pragma unroll
    for (int i = 0; i < 4; ++i) {
        if (i < nsc) {
            mi[i] = mlpart[(slot0 + i) * 128 + r];
            li[i] = mlpart[(slot0 + i) * 128 + 64 + r];
            M = fmaxf(M, mi[i]);
        }
    }
    float L = 0.f;
    f32x4 acc[4];
#pragma unroll
    for (int j = 0; j < 4; ++j) acc[j] = f32x4{0.f, 0.f, 0.f, 0.f};
#pragma unroll
    for (int i = 0; i < 4; ++i) {
        if (i < nsc) {
            float F = __expf(mi[i] - M);
            L += li[i] * F;
            const f32x4* orow = (const f32x4*)(opart + (slot0 + i) * 4096 +
                                               (size_t)r * 64 + qc * 16);
#pragma unroll
            for (int j = 0; j < 4; ++j) acc[j] += orow[j] * F;
        }
    }
    float rl = 1.0f / L;
    unsigned wb[8];
#pragma unroll
    for (int j = 0; j < 4; ++j) {
        wb[2 * j] = (unsigned)f2bf(acc[j][0] * rl) | ((unsigned)f2bf(acc[j][1] * rl) << 16);
        wb[2 * j + 1] = (unsigned)f2bf(acc[j][2] * rl) | ((unsigned)f2bf(acc[j][3] * rl) << 16);
    }
    ushort_t* dst = attout + ((size_t)(bb * TSEQ + qb * 64 + r)) * CC + hh * DH + qc * 16;
    ((uint4*)dst)[0] = make_uint4(wb[0], wb[1], wb[2], wb[3]);
    ((uint4*)dst)[1] = make_uint4(wb[4], wb[5], wb[6], wb[7]);
}

// ---------------------------------------------------------------------------
extern "C" void kernel_launch(void* const* d_in, const int* in_sizes, int n_in,
                              void* d_out, int out_size, void* d_ws, size_t ws_size,
                              hipStream_t stream)
{
    (void)in_sizes; (void)n_in; (void)out_size;
    const float* x     = (const float*)d_in[0];
    const float* ln1_g = (const float*)d_in[1];
    const float* ln1_b = (const float*)d_in[2];
    const float* Wq    = (const float*)d_in[3];
    const float* Wk    = (const float*)d_in[4];
    const float* Wv    = (const float*)d_in[5];
    const float* Wo    = (const float*)d_in[6];
    const float* bo    = (const float*)d_in[7];
    const float* ln2_g = (const float*)d_in[8];
    const float* ln2_b = (const float*)d_in[9];
    const float* W1    = (const float*)d_in[10];
    const float* b1    = (const float*)d_in[11];
    const float* W2    = (const float*)d_in[12];
    const float* b2    = (const float*)d_in[13];

    char* p = (char*)d_ws;
    ushort_t* hbuf  = (ushort_t*)p;  p += (size_t)BT * CC * 2;
    ushort_t* WqkvT = (ushort_t*)p;  p += (size_t)3 * CC * CC * 2;
    ushort_t* WoT   = (ushort_t*)p;  p += (size_t)CC * CC * 2;
    ushort_t* W1T   = (ushort_t*)p;  p += (size_t)CC * HID * 2;
    ushort_t* W2T   = (ushort_t*)p;  p += (size_t)HID * CC * 2;
    ushort_t* Qb    = (ushort_t*)p;  p += (size_t)BT * CC * 2;
    ushort_t* Kbuf  = (ushort_t*)p;  p += (size_t)BT * CC * 2;
    ushort_t* Vt    = (ushort_t*)p;  p += (size_t)BT * CC * 2;
    ushort_t* atto  = (ushort_t*)p;  p += (size_t)BT * CC * 2;
    float*    x1    = (float*)p;     p += (size_t)BT * CC * 4;
    ushort_t* h2    = (ushort_t*)p;  p += (size_t)BT * CC * 2;
    ushort_t* mid   = (ushort_t*)p;  p += (size_t)BT * HID * 2;
    float*    opart = (float*)p;     p += (size_t)4096 * 4096 * 4;   // 67 MB (flash partials, then FFN2 partials)
    float*    mlprt = (float*)p;     p += (size_t)4096 * 128 * 4;    // 2 MB
    const size_t need = (size_t)(p - (char*)d_ws);

    ushort_t* WqT = WqkvT;
    ushort_t* WkT = WqkvT + (size_t)CC * CC;
    ushort_t* WvT = WqkvT + (size_t)2 * CC * CC;

    dim3 blk(256);
    transpose_cvt<<<dim3(DH / 32, CC / 32, NH), blk, 0, stream>>>(Wq, WqT, CC, DH);
    transpose_cvt<<<dim3(DH / 32, CC / 32, NH), blk, 0, stream>>>(Wk, WkT, CC, DH);
    transpose_cvt<<<dim3(DH / 32, CC / 32, NH), blk, 0, stream>>>(Wv, WvT, CC, DH);
    transpose_cvt<<<dim3(CC / 32, CC / 32, 1), blk, 0, stream>>>(Wo, WoT, CC, CC);
    transpose_cvt<<<dim3(HID / 32, CC / 32, 1), blk, 0, stream>>>(W1, W1T, CC, HID);
    transpose_cvt<<<dim3(CC / 32, HID / 32, 1), blk, 0, stream>>>(W2, W2T, HID, CC);

    ln_kernel<<<dim3(BT), blk, 0, stream>>>(x, ln1_g, ln1_b, hbuf);
    gemm_tile<128, 128, 2, 2, 4, 4, 2><<<dim3(BT / 128, 3072 / 128), blk, 0, stream>>>(
        hbuf, WqkvT, 3072, CC, CC, CC, nullptr, nullptr, Qb, Kbuf, Vt);
    if (ws_size >= need) {
        flash_split<<<dim3(2 * NH, TSEQ / 64, 4), blk, 0, stream>>>(
            Qb, Kbuf, Vt, opart, mlprt, atto);
        flash_combine<<<dim3(2 * NH, TSEQ / 64 - 8), blk, 0, stream>>>(opart, mlprt, atto);
    } else {
        flash_attn<<<dim3(2 * NH, TSEQ / 64), blk, 0, stream>>>(Qb, Kbuf, Vt, atto);
    }
    gemm_tile<128, 64, 4, 1, 2, 4, 0><<<dim3(BT / 128, CC / 64), blk, 0, stream>>>(
        atto, WoT, CC, CC, CC, CC, bo, x, (void*)x1, nullptr, nullptr);
    ln_kernel<<<dim3(BT), blk, 0, stream>>>(x1, ln2_g, ln2_b, h2);
    gemm_tile<128, 128, 2, 2, 4, 4, 1><<<dim3(BT / 128, HID / 128), blk, 0, stream>>>(
        h2, W1T, HID, CC, CC, CC, b1, nullptr, (void*)mid, nullptr, nullptr);
    if (ws_size >= need) {
        // FFN2 split-K: 4 chunks of K=1024 -> f32 partials in opart (reused)
        gemm_tile<128, 64, 4, 1, 2, 4, 3><<<dim3(BT / 128, CC / 64, 4), blk, 0, stream>>>(
            mid, W2T, CC, HID / 4, HID, HID, nullptr, nullptr, (void*)opart, nullptr, nullptr);
        ffn2_combine<<<dim3(BT * CC / 4 / 256), blk, 0, stream>>>(opart, b2, x1, (float*)d_out);
    } else {
        gemm_tile<128, 64, 4, 1, 2, 4, 0><<<dim3(BT / 128, CC / 64), blk, 0, stream>>>(
            mid, W2T, CC, HID, HID, HID, b2, x1, d_out, nullptr, nullptr);
    }
}

// Round 10
// 255.708 us; speedup vs baseline: 1.1134x; 1.1134x over previous
//
#include <hip/hip_runtime.h>

typedef unsigned short ushort_t;
typedef __attribute__((ext_vector_type(8))) short short8;
typedef __attribute__((ext_vector_type(4))) float f32x4;

#define BT 4096
#define TSEQ 2048
#define CC 1024
#define NH 16
#define DH 64
#define HID 4096
#define ATT_SCALE 0.03125f   /* C^-0.5 = 1/32 (reference scales by C, not DH) */

__device__ __forceinline__ ushort_t f2bf(float f) {
    unsigned u = __float_as_uint(f);
    u = u + 0x7fffu + ((u >> 16) & 1u);
    return (ushort_t)(u >> 16);
}
__device__ __forceinline__ float bf2f(ushort_t u) {
    return __uint_as_float(((unsigned)u) << 16);
}

typedef const __attribute__((address_space(1))) unsigned int* gptr_t;
typedef __attribute__((address_space(3))) unsigned int* lptr_t;
__device__ __forceinline__ void gload_lds16(const void* g, void* l) {
    __builtin_amdgcn_global_load_lds((gptr_t)g, (lptr_t)l, 16, 0, 0);
}

// ---------------------------------------------------------------------------
// Tiled transpose + f32->bf16 convert:  in [R][Cn] f32  ->  out [Cn][R] bf16
// ---------------------------------------------------------------------------
__global__ __launch_bounds__(256) void transpose_cvt(
    const float* __restrict__ in, ushort_t* __restrict__ out, int R, int Cn)
{
    __shared__ float tile[32][33];
    size_t off = (size_t)blockIdx.z * R * Cn;
    int c0 = blockIdx.x * 32, r0 = blockIdx.y * 32;
    int tx = threadIdx.x & 31, ty = threadIdx.x >> 5;
#pragma unroll
    for (int q = 0; q < 4; ++q)
        tile[ty + 8 * q][tx] = in[off + (size_t)(r0 + ty + 8 * q) * Cn + c0 + tx];
    __syncthreads();
#pragma unroll
    for (int q = 0; q < 4; ++q)
        out[off + (size_t)(c0 + ty + 8 * q) * R + r0 + tx] = f2bf(tile[tx][ty + 8 * q]);
}

// ---------------------------------------------------------------------------
// LayerNorm row kernel: x f32 [rows][1024] -> out bf16.
// ---------------------------------------------------------------------------
__global__ __launch_bounds__(256) void ln_kernel(
    const float* __restrict__ x, const float* __restrict__ g,
    const float* __restrict__ b, ushort_t* __restrict__ out)
{
    int row = blockIdx.x;
    const float4 xv = ((const float4*)(x + (size_t)row * CC))[threadIdx.x];
    float s = xv.x + xv.y + xv.z + xv.w;
    float s2 = xv.x * xv.x + xv.y * xv.y + xv.z * xv.z + xv.w * xv.w;
#pragma unroll
    for (int d = 1; d < 64; d <<= 1) {
        s += __shfl_xor(s, d);
        s2 += __shfl_xor(s2, d);
    }
    __shared__ float ps[4], ps2[4];
    int w = threadIdx.x >> 6, lane = threadIdx.x & 63;
    if (lane == 0) { ps[w] = s; ps2[w] = s2; }
    __syncthreads();
    s = ps[0] + ps[1] + ps[2] + ps[3];
    s2 = ps2[0] + ps2[1] + ps2[2] + ps2[3];
    float mu = s * (1.0f / CC);
    float var = s2 * (1.0f / CC) - mu * mu;
    float rs = rsqrtf(var + 1e-5f);
    int c = threadIdx.x * 4;
    const float4 gv = ((const float4*)g)[threadIdx.x];
    const float4 bv = ((const float4*)b)[threadIdx.x];
    ushort_t u0 = f2bf((xv.x - mu) * rs * gv.x + bv.x);
    ushort_t u1 = f2bf((xv.y - mu) * rs * gv.y + bv.y);
    ushort_t u2 = f2bf((xv.z - mu) * rs * gv.z + bv.z);
    ushort_t u3 = f2bf((xv.w - mu) * rs * gv.w + bv.w);
    unsigned lo = (unsigned)u0 | ((unsigned)u1 << 16);
    unsigned hi = (unsigned)u2 | ((unsigned)u3 << 16);
    ((uint2*)(out + (size_t)row * CC + c))[0] = make_uint2(lo, hi);
}

// ---------------------------------------------------------------------------
// LDS-staged NT GEMM, double-buffered 2-phase with COUNTED vmcnt (T3/T4-min):
// per K-step: issue next stage -> vmcnt(L) [only current tile's loads] ->
// raw s_barrier -> ds_read+MFMA (setprio 1) -> raw s_barrier -> swap.
// The prefetch stays in flight across both barriers (never drained).
// MODE 0: f32 out = acc + bias[n] + resid[m][n]
// MODE 1: bf16 out = relu(acc + bias[n])
// MODE 2: QKV scatter (Q prescaled by ATT_SCALE)
// MODE 3: split-K bf16 partial at plane blockIdx.z (A/B column offset z*K)
// ---------------------------------------------------------------------------
template <int BM, int BN, int WM, int WN, int MR, int NR, int MODE>
__global__ __launch_bounds__(256) void gemm_tile(
    const ushort_t* __restrict__ A, const ushort_t* __restrict__ Bt,
    int N, int K, int lda, int ldb,
    const float* __restrict__ bias, const float* __restrict__ resid,
    void* __restrict__ out0, void* __restrict__ out1, void* __restrict__ out2)
{
    static_assert(WM * WN == 4 && WM * MR * 16 == BM && WN * NR * 16 == BN, "geom");
    __shared__ ushort_t As[2][BM * 32];
    __shared__ ushort_t Bs[2][BN * 32];

    const int t = threadIdx.x;
    const int w = t >> 6, lane = t & 63, g = lane >> 4, c = lane & 15;
    const int wr = w / WN, wc = w % WN;
    const int m0 = blockIdx.x * BM;
    const int n0 = blockIdx.y * BN;
    if (MODE == 3) {   // K-chunk column offset
        A += (size_t)blockIdx.z * K;
        Bt += (size_t)blockIdx.z * K;
    }

    f32x4 acc[MR][NR];
#pragma unroll
    for (int mi = 0; mi < MR; ++mi)
#pragma unroll
        for (int ni = 0; ni < NR; ++ni) acc[mi][ni] = f32x4{0.f, 0.f, 0.f, 0.f};

    const int arow = t >> 2, acol = (t & 3) * 8;
    const int aoff = (wr * MR * 16 + c) * 32 + g * 8;
    const int boff = (wc * NR * 16 + c) * 32 + g * 8;

#define STAGE(BUF, K0)                                                          \
    {                                                                           \
        _Pragma("unroll") for (int j = 0; j < BM / 64; ++j)                     \
            gload_lds16(A + (size_t)(m0 + j * 64 + arow) * lda + (K0) + acol,   \
                        As[BUF] + (size_t)j * 2048 + t * 8);                    \
        _Pragma("unroll") for (int j = 0; j < BN / 64; ++j)                     \
            gload_lds16(Bt + (size_t)(n0 + j * 64 + arow) * ldb + (K0) + acol,  \
                        Bs[BUF] + (size_t)j * 2048 + t * 8);                    \
    }

    STAGE(0, 0);
    int cur = 0;
    for (int k0 = 0; k0 < K; k0 += 32) {
        if (k0 + 32 < K) {
            STAGE(cur ^ 1, k0 + 32);
            // wait only the OLDEST L loads (current tile); prefetch stays in flight
            if constexpr (BM / 64 + BN / 64 == 4)
                asm volatile("s_waitcnt vmcnt(4)" ::: "memory");
            else
                asm volatile("s_waitcnt vmcnt(3)" ::: "memory");
        } else {
            asm volatile("s_waitcnt vmcnt(0)" ::: "memory");
        }
        __builtin_amdgcn_sched_barrier(0);
        __builtin_amdgcn_s_barrier();

        const ushort_t* Ard = As[cur] + aoff;
        const ushort_t* Brd = Bs[cur] + boff;
        short8 af[MR], bf[NR];
#pragma unroll
        for (int mi = 0; mi < MR; ++mi) af[mi] = *(const short8*)(Ard + mi * 512);
#pragma unroll
        for (int ni = 0; ni < NR; ++ni) bf[ni] = *(const short8*)(Brd + ni * 512);
        __builtin_amdgcn_s_setprio(1);
#pragma unroll
        for (int mi = 0; mi < MR; ++mi)
#pragma unroll
            for (int ni = 0; ni < NR; ++ni)
                acc[mi][ni] = __builtin_amdgcn_mfma_f32_16x16x32_bf16(
                    af[mi], bf[ni], acc[mi][ni], 0, 0, 0);
        __builtin_amdgcn_s_setprio(0);

        __builtin_amdgcn_sched_barrier(0);
        __builtin_amdgcn_s_barrier();   // reads of As[cur]/Bs[cur] done before restage
        cur ^= 1;
    }
#undef STAGE

#pragma unroll
    for (int mi = 0; mi < MR; ++mi)
#pragma unroll
        for (int ni = 0; ni < NR; ++ni)
#pragma unroll
            for (int i = 0; i < 4; ++i) {
                int row = m0 + wr * MR * 16 + mi * 16 + g * 4 + i;
                int col = n0 + wc * NR * 16 + ni * 16 + c;
                float v = acc[mi][ni][i];
                if (MODE == 0) {
                    v += bias[col] + resid[(size_t)row * N + col];
                    ((float*)out0)[(size_t)row * N + col] = v;
                } else if (MODE == 1) {
                    v += bias[col];
                    v = v > 0.f ? v : 0.f;
                    ((ushort_t*)out0)[(size_t)row * N + col] = f2bf(v);
                } else if (MODE == 3) {
                    ((ushort_t*)out0)[(size_t)blockIdx.z * BT * N + (size_t)row * N + col] =
                        f2bf(v);
                } else {
                    int bb = row >> 11, tt = row & (TSEQ - 1);
                    if (col < 1024) {
                        int head = col >> 6, d = col & 63;
                        ((ushort_t*)out0)[((size_t)(bb * NH + head) * TSEQ + tt) * DH + d] =
                            f2bf(v * ATT_SCALE);
                    } else if (col < 2048) {
                        int head = (col - 1024) >> 6, d = col & 63;
                        ((ushort_t*)out1)[((size_t)(bb * NH + head) * TSEQ + tt) * DH + d] = f2bf(v);
                    } else {
                        int head = (col - 2048) >> 6, d = col & 63;
                        ((ushort_t*)out2)[((size_t)(bb * NH + head) * DH + d) * TSEQ + tt] = f2bf(v);
                    }
                }
            }
}

// ---------------------------------------------------------------------------
// FFN2 combine: out[m][n] = sum_{z<2} bf16 parts[z][m][n] + bias[n] + resid
// grid 2048 x 256; 8 elements per thread.
// ---------------------------------------------------------------------------
__global__ __launch_bounds__(256) void ffn2_combine(
    const ushort_t* __restrict__ parts, const float* __restrict__ bias,
    const float* __restrict__ resid, float* __restrict__ out)
{
    const size_t off = ((size_t)blockIdx.x * 256 + threadIdx.x) * 8;
    const int col = (int)(off & 1023);
    short8 p0 = *(const short8*)(parts + off);
    short8 p1 = *(const short8*)(parts + (size_t)BT * CC + off);
    float4 r0 = ((const float4*)(resid + off))[0];
    float4 r1 = ((const float4*)(resid + off + 4))[0];
    float4 b0 = ((const float4*)(bias + col))[0];
    float4 b1 = ((const float4*)(bias + col + 4))[0];
    float o[8];
#pragma unroll
    for (int j = 0; j < 8; ++j)
        o[j] = bf2f((ushort_t)p0[j]) + bf2f((ushort_t)p1[j]);
    float4 w0 = make_float4(o[0] + b0.x + r0.x, o[1] + b0.y + r0.y,
                            o[2] + b0.z + r0.z, o[3] + b0.w + r0.w);
    float4 w1 = make_float4(o[4] + b1.x + r1.x, o[5] + b1.y + r1.y,
                            o[6] + b1.z + r1.z, o[7] + b1.w + r1.w);
    ((float4*)(out + off))[0] = w0;
    ((float4*)(out + off + 4))[0] = w1;
}

// ---------------------------------------------------------------------------
// Split flash: K/V tiles staged ONCE per block into LDS (global_load_lds,
// inverse-swizzled global source, byte ^= (row&7)<<4), shared by all 4 waves.
// grid (B*H, T/64, 4 s-chunks of 8 tiles), block 256.
// ---------------------------------------------------------------------------
__global__ __launch_bounds__(256) void flash_split(
    const ushort_t* __restrict__ Q, const ushort_t* __restrict__ Kb,
    const ushort_t* __restrict__ Vt, float* __restrict__ opart,
    float* __restrict__ mlpart, ushort_t* __restrict__ attout)
{
    __shared__ ushort_t Ks[64 * 64];        // [s_loc][d], rows 128 B, swizzled
    __shared__ ushort_t Vs[64 * 64];        // [d][s_loc], rows 128 B, swizzled
    __shared__ ushort_t Plds[4][16 * 72];
    const int t = threadIdx.x;
    const int w = t >> 6, lane = t & 63;
    const int g = lane >> 4, c = lane & 15;
    const int bh = blockIdx.x, qb = blockIdx.y, sc = blockIdx.z;
    if (sc * 8 > qb) return;                // beyond causal bound
    const int bb = bh >> 4, hh = bh & 15;
    const int q0 = qb * 64 + w * 16;
    const ushort_t* qp = Q + (size_t)bh * TSEQ * DH;
    const char* kpB = (const char*)(Kb + (size_t)bh * TSEQ * DH);
    const char* vpB = (const char*)(Vt + (size_t)bh * DH * TSEQ);

    const short8 bq0 = *(const short8*)(qp + (size_t)(q0 + c) * DH + g * 8);
    const short8 bq1 = *(const short8*)(qp + (size_t)(q0 + c) * DH + 32 + g * 8);

    float m_ = -INFINITY, l_ = 0.f;
    f32x4 o[4];
#pragma unroll
    for (int nf = 0; nf < 4; ++nf) o[nf] = f32x4{0.f, 0.f, 0.f, 0.f};

    const int st0 = sc * 8;
    const int send = (st0 + 7 < qb) ? st0 + 7 : qb;
    ushort_t* pw = &Plds[w][c * 72];
    const unsigned bxor = (unsigned)((c & 7) << 4);   // read-side swizzle

    const int srow = t >> 3, sb = (t & 7) * 16;
#define STAGE_KV(ST)                                                                \
    {                                                                               \
        const int S0_ = (ST) * 64;                                                  \
        _Pragma("unroll") for (int j = 0; j < 2; ++j) {                             \
            int r = j * 32 + srow;                                                  \
            int bs = sb ^ ((r & 7) << 4);                                           \
            gload_lds16(kpB + (size_t)(S0_ + r) * 128 + bs,                         \
                        (char*)Ks + r * 128 + sb);                                  \
            gload_lds16(vpB + (size_t)r * (TSEQ * 2) + S0_ * 2 + bs,                \
                        (char*)Vs + r * 128 + sb);                                  \
        }                                                                           \
    }

    STAGE_KV(st0);
    for (int st = st0; st <= send; ++st) {
        const int S0 = st * 64;
        __syncthreads();   // staged data visible (drains vmcnt)

        __builtin_amdgcn_s_setprio(1);
        f32x4 sa[4];
#pragma unroll
        for (int sub = 0; sub < 4; ++sub) {
            const char* kr = (const char*)Ks + (16 * sub + c) * 128;
            short8 k0 = *(const short8*)(kr + ((g * 16) ^ bxor));
            short8 k1 = *(const short8*)(kr + ((64 + g * 16) ^ bxor));
            f32x4 t0 = f32x4{0.f, 0.f, 0.f, 0.f};
            t0 = __builtin_amdgcn_mfma_f32_16x16x32_bf16(k0, bq0, t0, 0, 0, 0);
            t0 = __builtin_amdgcn_mfma_f32_16x16x32_bf16(k1, bq1, t0, 0, 0, 0);
            sa[sub] = t0;
        }
        __builtin_amdgcn_s_setprio(0);

        float pvv[16];
#pragma unroll
        for (int sub = 0; sub < 4; ++sub)
#pragma unroll
            for (int i = 0; i < 4; ++i) pvv[4 * sub + i] = sa[sub][i];
        if (st == qb) {   // diagonal tile
#pragma unroll
            for (int sub = 0; sub < 4; ++sub)
#pragma unroll
                for (int i = 0; i < 4; ++i)
                    if (S0 + 16 * sub + 4 * g + i > q0 + c) pvv[4 * sub + i] = -INFINITY;
        }
        float tmax = pvv[0];
#pragma unroll
        for (int j = 1; j < 16; ++j) tmax = fmaxf(tmax, pvv[j]);
        tmax = fmaxf(tmax, __shfl_xor(tmax, 16));
        tmax = fmaxf(tmax, __shfl_xor(tmax, 32));
        if (!__all(tmax - m_ <= 8.0f)) {   // defer-max
            float mn = fmaxf(m_, tmax);
            float fac = __expf(m_ - mn);
            m_ = mn;
            l_ *= fac;
#pragma unroll
            for (int i = 0; i < 4; ++i) {
                float fr = __shfl(fac, 4 * g + i);
#pragma unroll
                for (int nf = 0; nf < 4; ++nf) o[nf][i] *= fr;
            }
        }
        float pp[16], rs = 0.f;
#pragma unroll
        for (int j = 0; j < 16; ++j) { pp[j] = __expf(pvv[j] - m_); rs += pp[j]; }
        rs += __shfl_xor(rs, 16);
        rs += __shfl_xor(rs, 32);
        l_ += rs;

        // P -> bf16 (truncate), LDS transpose: row q=c gets s_local 16sub+4g+i
#pragma unroll
        for (int sub = 0; sub < 4; ++sub) {
            unsigned lo = (__float_as_uint(pp[4 * sub + 0]) >> 16) |
                          (__float_as_uint(pp[4 * sub + 1]) & 0xffff0000u);
            unsigned hi = (__float_as_uint(pp[4 * sub + 2]) >> 16) |
                          (__float_as_uint(pp[4 * sub + 3]) & 0xffff0000u);
            *(uint2*)(pw + 16 * sub + 4 * g) = make_uint2(lo, hi);
        }
        asm volatile("s_waitcnt lgkmcnt(0)" ::: "memory");
        short8 pa0 = *(const short8*)(&Plds[w][c * 72 + g * 8]);
        short8 pa1 = *(const short8*)(&Plds[w][c * 72 + 32 + g * 8]);

        __builtin_amdgcn_s_setprio(1);
#pragma unroll
        for (int nf = 0; nf < 4; ++nf) {
            const char* vr = (const char*)Vs + (nf * 16 + c) * 128;
            short8 v0 = *(const short8*)(vr + ((g * 16) ^ bxor));
            short8 v1 = *(const short8*)(vr + ((64 + g * 16) ^ bxor));
            o[nf] = __builtin_amdgcn_mfma_f32_16x16x32_bf16(pa0, v0, o[nf], 0, 0, 0);
            o[nf] = __builtin_amdgcn_mfma_f32_16x16x32_bf16(pa1, v1, o[nf], 0, 0, 0);
        }
        __builtin_amdgcn_s_setprio(0);

        __syncthreads();   // all LDS reads done before restage
        if (st < send) STAGE_KV(st + 1);
    }
#undef STAGE_KV

    if (qb < 8) {   // single chunk: finalize directly
#pragma unroll
        for (int i = 0; i < 4; ++i) {
            float rl = 1.0f / __shfl(l_, 4 * g + i);
            int tt = q0 + 4 * g + i;
#pragma unroll
            for (int nf = 0; nf < 4; ++nf)
                attout[((size_t)(bb * TSEQ + tt)) * CC + hh * DH + nf * 16 + c] =
                    f2bf(o[nf][i] * rl);
        }
    } else {
        const size_t slot = (size_t)(bh * 32 + qb) * 4 + sc;
        float* op = opart + slot * 4096;
#pragma unroll
        for (int nf = 0; nf < 4; ++nf)
#pragma unroll
            for (int i = 0; i < 4; ++i)
                op[(size_t)(w * 16 + 4 * g + i) * 64 + nf * 16 + c] = o[nf][i];
        if (g == 0) {
            mlpart[slot * 128 + w * 16 + c] = m_;
            mlpart[slot * 128 + 64 + w * 16 + c] = l_;
        }
    }
}

// ---------------------------------------------------------------------------
// Combine partials for qb >= 8.  grid (B*H, 24) -> qb = blockIdx.y + 8.
// ---------------------------------------------------------------------------
__global__ __launch_bounds__(256) void flash_combine(
    const float* __restrict__ opart, const float* __restrict__ mlpart,
    ushort_t* __restrict__ attout)
{
    const int bh = blockIdx.x, qb = blockIdx.y + 8;
    const int bb = bh >> 4, hh = bh & 15;
    const int nsc = (qb >> 3) + 1;      // 2..4
    const int t = threadIdx.x, r = t >> 2, qc = t & 3;
    const size_t slot0 = (size_t)(bh * 32 + qb) * 4;

    float mi[4], li[4];
    float M = -INFINITY;
#pragma unroll
    for (int i = 0; i < 4; ++i) {
        if (i < nsc) {
            mi[i] = mlpart[(slot0 + i) * 128 + r];
            li[i] = mlpart[(slot0 + i) * 128 + 64 + r];
            M = fmaxf(M, mi[i]);
        }
    }
    float L = 0.f;
    f32x4 acc[4];
#pragma unroll
    for (int j = 0; j < 4; ++j) acc[j] = f32x4{0.f, 0.f, 0.f, 0.f};
#pragma unroll
    for (int i = 0; i < 4; ++i) {
        if (i < nsc) {
            float F = __expf(mi[i] - M);
            L += li[i] * F;
            const f32x4* orow = (const f32x4*)(opart + (slot0 + i) * 4096 +
                                               (size_t)r * 64 + qc * 16);
#pragma unroll
            for (int j = 0; j < 4; ++j) acc[j] += orow[j] * F;
        }
    }
    float rl = 1.0f / L;
    unsigned wb[8];
#pragma unroll
    for (int j = 0; j < 4; ++j) {
        wb[2 * j] = (unsigned)f2bf(acc[j][0] * rl) | ((unsigned)f2bf(acc[j][1] * rl) << 16);
        wb[2 * j + 1] = (unsigned)f2bf(acc[j][2] * rl) | ((unsigned)f2bf(acc[j][3] * rl) << 16);
    }
    ushort_t* dst = attout + ((size_t)(bb * TSEQ + qb * 64 + r)) * CC + hh * DH + qc * 16;
    ((uint4*)dst)[0] = make_uint4(wb[0], wb[1], wb[2], wb[3]);
    ((uint4*)dst)[1] = make_uint4(wb[4], wb[5], wb[6], wb[7]);
}

// ---------------------------------------------------------------------------
extern "C" void kernel_launch(void* const* d_in, const int* in_sizes, int n_in,
                              void* d_out, int out_size, void* d_ws, size_t ws_size,
                              hipStream_t stream)
{
    (void)in_sizes; (void)n_in; (void)out_size; (void)ws_size;
    const float* x     = (const float*)d_in[0];
    const float* ln1_g = (const float*)d_in[1];
    const float* ln1_b = (const float*)d_in[2];
    const float* Wq    = (const float*)d_in[3];
    const float* Wk    = (const float*)d_in[4];
    const float* Wv    = (const float*)d_in[5];
    const float* Wo    = (const float*)d_in[6];
    const float* bo    = (const float*)d_in[7];
    const float* ln2_g = (const float*)d_in[8];
    const float* ln2_b = (const float*)d_in[9];
    const float* W1    = (const float*)d_in[10];
    const float* b1    = (const float*)d_in[11];
    const float* W2    = (const float*)d_in[12];
    const float* b2    = (const float*)d_in[13];

    char* p = (char*)d_ws;
    ushort_t* hbuf  = (ushort_t*)p;  p += (size_t)BT * CC * 2;
    ushort_t* WqkvT = (ushort_t*)p;  p += (size_t)3 * CC * CC * 2;
    ushort_t* WoT   = (ushort_t*)p;  p += (size_t)CC * CC * 2;
    ushort_t* W1T   = (ushort_t*)p;  p += (size_t)CC * HID * 2;
    ushort_t* W2T   = (ushort_t*)p;  p += (size_t)HID * CC * 2;
    ushort_t* Qb    = (ushort_t*)p;  p += (size_t)BT * CC * 2;
    ushort_t* Kbuf  = (ushort_t*)p;  p += (size_t)BT * CC * 2;
    ushort_t* Vt    = (ushort_t*)p;  p += (size_t)BT * CC * 2;
    ushort_t* atto  = (ushort_t*)p;  p += (size_t)BT * CC * 2;
    float*    x1    = (float*)p;     p += (size_t)BT * CC * 4;
    ushort_t* h2    = (ushort_t*)p;  p += (size_t)BT * CC * 2;
    ushort_t* mid   = (ushort_t*)p;  p += (size_t)BT * HID * 2;
    float*    opart = (float*)p;     p += (size_t)4096 * 4096 * 4;   // flash partials / FFN2 bf16 partials
    float*    mlprt = (float*)p;     p += (size_t)4096 * 128 * 4;

    ushort_t* WqT = WqkvT;
    ushort_t* WkT = WqkvT + (size_t)CC * CC;
    ushort_t* WvT = WqkvT + (size_t)2 * CC * CC;

    dim3 blk(256);
    transpose_cvt<<<dim3(DH / 32, CC / 32, NH), blk, 0, stream>>>(Wq, WqT, CC, DH);
    transpose_cvt<<<dim3(DH / 32, CC / 32, NH), blk, 0, stream>>>(Wk, WkT, CC, DH);
    transpose_cvt<<<dim3(DH / 32, CC / 32, NH), blk, 0, stream>>>(Wv, WvT, CC, DH);
    transpose_cvt<<<dim3(CC / 32, CC / 32, 1), blk, 0, stream>>>(Wo, WoT, CC, CC);
    transpose_cvt<<<dim3(HID / 32, CC / 32, 1), blk, 0, stream>>>(W1, W1T, CC, HID);
    transpose_cvt<<<dim3(CC / 32, HID / 32, 1), blk, 0, stream>>>(W2, W2T, HID, CC);

    ln_kernel<<<dim3(BT), blk, 0, stream>>>(x, ln1_g, ln1_b, hbuf);
    gemm_tile<128, 128, 2, 2, 4, 4, 2><<<dim3(BT / 128, 3072 / 128), blk, 0, stream>>>(
        hbuf, WqkvT, 3072, CC, CC, CC, nullptr, nullptr, Qb, Kbuf, Vt);
    flash_split<<<dim3(2 * NH, TSEQ / 64, 4), blk, 0, stream>>>(
        Qb, Kbuf, Vt, opart, mlprt, atto);
    flash_combine<<<dim3(2 * NH, TSEQ / 64 - 8), blk, 0, stream>>>(opart, mlprt, atto);
    gemm_tile<128, 64, 4, 1, 2, 4, 0><<<dim3(BT / 128, CC / 64), blk, 0, stream>>>(
        atto, WoT, CC, CC, CC, CC, bo, x, (void*)x1, nullptr, nullptr);
    ln_kernel<<<dim3(BT), blk, 0, stream>>>(x1, ln2_g, ln2_b, h2);
    gemm_tile<128, 128, 2, 2, 4, 4, 1><<<dim3(BT / 128, HID / 128), blk, 0, stream>>>(
        h2, W1T, HID, CC, CC, CC, b1, nullptr, (void*)mid, nullptr, nullptr);
    // FFN2 split-K: 2 chunks of K=2048 -> bf16 partials in opart (reused)
    gemm_tile<128, 64, 4, 1, 2, 4, 3><<<dim3(BT / 128, CC / 64, 2), blk, 0, stream>>>(
        mid, W2T, CC, HID / 2, HID, HID, nullptr, nullptr, (void*)opart, nullptr, nullptr);
    ffn2_combine<<<dim3(BT * CC / 8 / 256), blk, 0, stream>>>(
        (const ushort_t*)opart, b2, x1, (float*)d_out);
}

// Round 11
// 253.470 us; speedup vs baseline: 1.1232x; 1.0088x over previous
//
#include <hip/hip_runtime.h>

typedef unsigned short ushort_t;
typedef __attribute__((ext_vector_type(8))) short short8;
typedef __attribute__((ext_vector_type(4))) float f32x4;

#define BT 4096
#define TSEQ 2048
#define CC 1024
#define NH 16
#define DH 64
#define HID 4096
#define ATT_SCALE 0.03125f   /* C^-0.5 = 1/32 (reference scales by C, not DH) */

__device__ __forceinline__ ushort_t f2bf(float f) {
    unsigned u = __float_as_uint(f);
    u = u + 0x7fffu + ((u >> 16) & 1u);
    return (ushort_t)(u >> 16);
}
__device__ __forceinline__ float bf2f(ushort_t u) {
    return __uint_as_float(((unsigned)u) << 16);
}

typedef const __attribute__((address_space(1))) unsigned int* gptr_t;
typedef __attribute__((address_space(3))) unsigned int* lptr_t;
__device__ __forceinline__ void gload_lds16(const void* g, void* l) {
    __builtin_amdgcn_global_load_lds((gptr_t)g, (lptr_t)l, 16, 0, 0);
}

template <int N> __device__ __forceinline__ void vmcnt_wait() {
    if constexpr (N == 0)      asm volatile("s_waitcnt vmcnt(0)" ::: "memory");
    else if constexpr (N == 3) asm volatile("s_waitcnt vmcnt(3)" ::: "memory");
    else if constexpr (N == 4) asm volatile("s_waitcnt vmcnt(4)" ::: "memory");
    else if constexpr (N == 6) asm volatile("s_waitcnt vmcnt(6)" ::: "memory");
    else if constexpr (N == 8) asm volatile("s_waitcnt vmcnt(8)" ::: "memory");
    else static_assert(N == 0, "unsupported vmcnt");
}

// ---------------------------------------------------------------------------
// Tiled transpose + f32->bf16 convert:  in [R][Cn] f32  ->  out [Cn][R] bf16
// ---------------------------------------------------------------------------
__global__ __launch_bounds__(256) void transpose_cvt(
    const float* __restrict__ in, ushort_t* __restrict__ out, int R, int Cn)
{
    __shared__ float tile[32][33];
    size_t off = (size_t)blockIdx.z * R * Cn;
    int c0 = blockIdx.x * 32, r0 = blockIdx.y * 32;
    int tx = threadIdx.x & 31, ty = threadIdx.x >> 5;
#pragma unroll
    for (int q = 0; q < 4; ++q)
        tile[ty + 8 * q][tx] = in[off + (size_t)(r0 + ty + 8 * q) * Cn + c0 + tx];
    __syncthreads();
#pragma unroll
    for (int q = 0; q < 4; ++q)
        out[off + (size_t)(c0 + ty + 8 * q) * R + r0 + tx] = f2bf(tile[tx][ty + 8 * q]);
}

// QKV weight transpose, merged: z = mat*16 + head; [C][64] -> [64][C] per head
__global__ __launch_bounds__(256) void transpose_qkv(
    const float* __restrict__ Wq, const float* __restrict__ Wk,
    const float* __restrict__ Wv, ushort_t* __restrict__ WqkvT)
{
    __shared__ float tile[32][33];
    int z = blockIdx.z, mat = z >> 4, head = z & 15;
    const float* in = (mat == 0 ? Wq : (mat == 1 ? Wk : Wv)) + (size_t)head * CC * DH;
    ushort_t* out = WqkvT + (size_t)z * DH * CC;
    int c0 = blockIdx.x * 32, r0 = blockIdx.y * 32;
    int tx = threadIdx.x & 31, ty = threadIdx.x >> 5;
#pragma unroll
    for (int q = 0; q < 4; ++q)
        tile[ty + 8 * q][tx] = in[(size_t)(r0 + ty + 8 * q) * DH + c0 + tx];
    __syncthreads();
#pragma unroll
    for (int q = 0; q < 4; ++q)
        out[(size_t)(c0 + ty + 8 * q) * CC + r0 + tx] = f2bf(tile[tx][ty + 8 * q]);
}

// ---------------------------------------------------------------------------
// LayerNorm row kernel: x f32 [rows][1024] -> out bf16.
// ---------------------------------------------------------------------------
__global__ __launch_bounds__(256) void ln_kernel(
    const float* __restrict__ x, const float* __restrict__ g,
    const float* __restrict__ b, ushort_t* __restrict__ out)
{
    int row = blockIdx.x;
    const float4 xv = ((const float4*)(x + (size_t)row * CC))[threadIdx.x];
    float s = xv.x + xv.y + xv.z + xv.w;
    float s2 = xv.x * xv.x + xv.y * xv.y + xv.z * xv.z + xv.w * xv.w;
#pragma unroll
    for (int d = 1; d < 64; d <<= 1) {
        s += __shfl_xor(s, d);
        s2 += __shfl_xor(s2, d);
    }
    __shared__ float ps[4], ps2[4];
    int w = threadIdx.x >> 6, lane = threadIdx.x & 63;
    if (lane == 0) { ps[w] = s; ps2[w] = s2; }
    __syncthreads();
    s = ps[0] + ps[1] + ps[2] + ps[3];
    s2 = ps2[0] + ps2[1] + ps2[2] + ps2[3];
    float mu = s * (1.0f / CC);
    float var = s2 * (1.0f / CC) - mu * mu;
    float rs = rsqrtf(var + 1e-5f);
    int c = threadIdx.x * 4;
    const float4 gv = ((const float4*)g)[threadIdx.x];
    const float4 bv = ((const float4*)b)[threadIdx.x];
    ushort_t u0 = f2bf((xv.x - mu) * rs * gv.x + bv.x);
    ushort_t u1 = f2bf((xv.y - mu) * rs * gv.y + bv.y);
    ushort_t u2 = f2bf((xv.z - mu) * rs * gv.z + bv.z);
    ushort_t u3 = f2bf((xv.w - mu) * rs * gv.w + bv.w);
    unsigned lo = (unsigned)u0 | ((unsigned)u1 << 16);
    unsigned hi = (unsigned)u2 | ((unsigned)u3 << 16);
    ((uint2*)(out + (size_t)row * CC + c))[0] = make_uint2(lo, hi);
}

// ---------------------------------------------------------------------------
// LDS-staged NT GEMM, depth-D ring buffer with COUNTED vmcnt:
// prologue stages D-1 tiles; step t stages tile t+D-1 into the freed buffer,
// then waits vmcnt((D-1)*L) -> only tile t certified, D-1 tiles in flight.
// MODE 0: f32 out = acc + bias[n] + resid[m][n]
// MODE 1: bf16 out = relu(acc + bias[n])
// MODE 2: QKV scatter (Q prescaled by ATT_SCALE)
// MODE 3: split-K bf16 partial at plane blockIdx.z (A/B column offset z*K)
// ---------------------------------------------------------------------------
template <int BM, int BN, int WM, int WN, int MR, int NR, int MODE, int D>
__global__ __launch_bounds__(256) void gemm_tile(
    const ushort_t* __restrict__ A, const ushort_t* __restrict__ Bt,
    int N, int K, int lda, int ldb,
    const float* __restrict__ bias, const float* __restrict__ resid,
    void* __restrict__ out0, void* __restrict__ out1, void* __restrict__ out2)
{
    static_assert(WM * WN == 4 && WM * MR * 16 == BM && WN * NR * 16 == BN, "geom");
    constexpr int L = BM / 64 + BN / 64;   // gload_lds per thread per stage
    __shared__ ushort_t As[D][BM * 32];
    __shared__ ushort_t Bs[D][BN * 32];

    const int t = threadIdx.x;
    const int w = t >> 6, lane = t & 63, g = lane >> 4, c = lane & 15;
    const int wr = w / WN, wc = w % WN;
    const int m0 = blockIdx.x * BM;
    const int n0 = blockIdx.y * BN;
    if (MODE == 3) {   // K-chunk column offset
        A += (size_t)blockIdx.z * K;
        Bt += (size_t)blockIdx.z * K;
    }

    f32x4 acc[MR][NR];
#pragma unroll
    for (int mi = 0; mi < MR; ++mi)
#pragma unroll
        for (int ni = 0; ni < NR; ++ni) acc[mi][ni] = f32x4{0.f, 0.f, 0.f, 0.f};

    const int arow = t >> 2, acol = (t & 3) * 8;
    const int aoff = (wr * MR * 16 + c) * 32 + g * 8;
    const int boff = (wc * NR * 16 + c) * 32 + g * 8;

#define STAGE(BUF, K0)                                                          \
    {                                                                           \
        _Pragma("unroll") for (int j = 0; j < BM / 64; ++j)                     \
            gload_lds16(A + (size_t)(m0 + j * 64 + arow) * lda + (K0) + acol,   \
                        As[BUF] + (size_t)j * 2048 + t * 8);                    \
        _Pragma("unroll") for (int j = 0; j < BN / 64; ++j)                     \
            gload_lds16(Bt + (size_t)(n0 + j * 64 + arow) * ldb + (K0) + acol,  \
                        Bs[BUF] + (size_t)j * 2048 + t * 8);                    \
    }

    const int nt = K >> 5;
#pragma unroll
    for (int d = 0; d < D - 1; ++d) STAGE(d, d * 32);

    int cur = 0;
    for (int ti = 0; ti < nt; ++ti) {
        const int ahead = nt - 1 - ti;
        if (ahead >= D - 1) {
            const int stg = (cur == 0) ? D - 1 : cur - 1;   // buffer freed last step
            STAGE(stg, (ti + D - 1) * 32);
            vmcnt_wait<(D - 1) * L>();
        } else if (D == 3 && ahead == 1) {
            vmcnt_wait<L>();
        } else {
            vmcnt_wait<0>();
        }
        __builtin_amdgcn_sched_barrier(0);
        __builtin_amdgcn_s_barrier();

        const ushort_t* Ard = As[cur] + aoff;
        const ushort_t* Brd = Bs[cur] + boff;
        short8 af[MR], bf[NR];
#pragma unroll
        for (int mi = 0; mi < MR; ++mi) af[mi] = *(const short8*)(Ard + mi * 512);
#pragma unroll
        for (int ni = 0; ni < NR; ++ni) bf[ni] = *(const short8*)(Brd + ni * 512);
        __builtin_amdgcn_s_setprio(1);
#pragma unroll
        for (int mi = 0; mi < MR; ++mi)
#pragma unroll
            for (int ni = 0; ni < NR; ++ni)
                acc[mi][ni] = __builtin_amdgcn_mfma_f32_16x16x32_bf16(
                    af[mi], bf[ni], acc[mi][ni], 0, 0, 0);
        __builtin_amdgcn_s_setprio(0);

        __builtin_amdgcn_sched_barrier(0);
        __builtin_amdgcn_s_barrier();   // all reads of As[cur]/Bs[cur] done
        cur = (cur + 1 == D) ? 0 : cur + 1;
    }
#undef STAGE

#pragma unroll
    for (int mi = 0; mi < MR; ++mi)
#pragma unroll
        for (int ni = 0; ni < NR; ++ni)
#pragma unroll
            for (int i = 0; i < 4; ++i) {
                int row = m0 + wr * MR * 16 + mi * 16 + g * 4 + i;
                int col = n0 + wc * NR * 16 + ni * 16 + c;
                float v = acc[mi][ni][i];
                if (MODE == 0) {
                    v += bias[col] + resid[(size_t)row * N + col];
                    ((float*)out0)[(size_t)row * N + col] = v;
                } else if (MODE == 1) {
                    v += bias[col];
                    v = v > 0.f ? v : 0.f;
                    ((ushort_t*)out0)[(size_t)row * N + col] = f2bf(v);
                } else if (MODE == 3) {
                    ((ushort_t*)out0)[(size_t)blockIdx.z * BT * N + (size_t)row * N + col] =
                        f2bf(v);
                } else {
                    int bb = row >> 11, tt = row & (TSEQ - 1);
                    if (col < 1024) {
                        int head = col >> 6, d = col & 63;
                        ((ushort_t*)out0)[((size_t)(bb * NH + head) * TSEQ + tt) * DH + d] =
                            f2bf(v * ATT_SCALE);
                    } else if (col < 2048) {
                        int head = (col - 1024) >> 6, d = col & 63;
                        ((ushort_t*)out1)[((size_t)(bb * NH + head) * TSEQ + tt) * DH + d] = f2bf(v);
                    } else {
                        int head = (col - 2048) >> 6, d = col & 63;
                        ((ushort_t*)out2)[((size_t)(bb * NH + head) * DH + d) * TSEQ + tt] = f2bf(v);
                    }
                }
            }
}

// ---------------------------------------------------------------------------
// FFN2 combine: out[m][n] = sum_{z<2} bf16 parts[z][m][n] + bias[n] + resid
// ---------------------------------------------------------------------------
__global__ __launch_bounds__(256) void ffn2_combine(
    const ushort_t* __restrict__ parts, const float* __restrict__ bias,
    const float* __restrict__ resid, float* __restrict__ out)
{
    const size_t off = ((size_t)blockIdx.x * 256 + threadIdx.x) * 8;
    const int col = (int)(off & 1023);
    short8 p0 = *(const short8*)(parts + off);
    short8 p1 = *(const short8*)(parts + (size_t)BT * CC + off);
    float4 r0 = ((const float4*)(resid + off))[0];
    float4 r1 = ((const float4*)(resid + off + 4))[0];
    float4 b0 = ((const float4*)(bias + col))[0];
    float4 b1 = ((const float4*)(bias + col + 4))[0];
    float o[8];
#pragma unroll
    for (int j = 0; j < 8; ++j)
        o[j] = bf2f((ushort_t)p0[j]) + bf2f((ushort_t)p1[j]);
    float4 w0 = make_float4(o[0] + b0.x + r0.x, o[1] + b0.y + r0.y,
                            o[2] + b0.z + r0.z, o[3] + b0.w + r0.w);
    float4 w1 = make_float4(o[4] + b1.x + r1.x, o[5] + b1.y + r1.y,
                            o[6] + b1.z + r1.z, o[7] + b1.w + r1.w);
    ((float4*)(out + off))[0] = w0;
    ((float4*)(out + off + 4))[0] = w1;
}

// ---------------------------------------------------------------------------
// Split flash: K/V tiles staged ONCE per block into LDS (global_load_lds,
// inverse-swizzled global source, byte ^= (row&7)<<4), shared by all 4 waves.
// grid (B*H, T/64, 4 s-chunks of 8 tiles), block 256.
// ---------------------------------------------------------------------------
__global__ __launch_bounds__(256) void flash_split(
    const ushort_t* __restrict__ Q, const ushort_t* __restrict__ Kb,
    const ushort_t* __restrict__ Vt, float* __restrict__ opart,
    float* __restrict__ mlpart, ushort_t* __restrict__ attout)
{
    __shared__ ushort_t Ks[64 * 64];        // [s_loc][d], rows 128 B, swizzled
    __shared__ ushort_t Vs[64 * 64];        // [d][s_loc], rows 128 B, swizzled
    __shared__ ushort_t Plds[4][16 * 72];
    const int t = threadIdx.x;
    const int w = t >> 6, lane = t & 63;
    const int g = lane >> 4, c = lane & 15;
    const int bh = blockIdx.x, qb = blockIdx.y, sc = blockIdx.z;
    if (sc * 8 > qb) return;                // beyond causal bound
    const int bb = bh >> 4, hh = bh & 15;
    const int q0 = qb * 64 + w * 16;
    const ushort_t* qp = Q + (size_t)bh * TSEQ * DH;
    const char* kpB = (const char*)(Kb + (size_t)bh * TSEQ * DH);
    const char* vpB = (const char*)(Vt + (size_t)bh * DH * TSEQ);

    const short8 bq0 = *(const short8*)(qp + (size_t)(q0 + c) * DH + g * 8);
    const short8 bq1 = *(const short8*)(qp + (size_t)(q0 + c) * DH + 32 + g * 8);

    float m_ = -INFINITY, l_ = 0.f;
    f32x4 o[4];
#pragma unroll
    for (int nf = 0; nf < 4; ++nf) o[nf] = f32x4{0.f, 0.f, 0.f, 0.f};

    const int st0 = sc * 8;
    const int send = (st0 + 7 < qb) ? st0 + 7 : qb;
    ushort_t* pw = &Plds[w][c * 72];
    const unsigned bxor = (unsigned)((c & 7) << 4);   // read-side swizzle

    const int srow = t >> 3, sb = (t & 7) * 16;
#define STAGE_KV(ST)                                                                \
    {                                                                               \
        const int S0_ = (ST) * 64;                                                  \
        _Pragma("unroll") for (int j = 0; j < 2; ++j) {                             \
            int r = j * 32 + srow;                                                  \
            int bs = sb ^ ((r & 7) << 4);                                           \
            gload_lds16(kpB + (size_t)(S0_ + r) * 128 + bs,                         \
                        (char*)Ks + r * 128 + sb);                                  \
            gload_lds16(vpB + (size_t)r * (TSEQ * 2) + S0_ * 2 + bs,                \
                        (char*)Vs + r * 128 + sb);                                  \
        }                                                                           \
    }

    STAGE_KV(st0);
    for (int st = st0; st <= send; ++st) {
        const int S0 = st * 64;
        __syncthreads();   // staged data visible (drains vmcnt)

        __builtin_amdgcn_s_setprio(1);
        f32x4 sa[4];
#pragma unroll
        for (int sub = 0; sub < 4; ++sub) {
            const char* kr = (const char*)Ks + (16 * sub + c) * 128;
            short8 k0 = *(const short8*)(kr + ((g * 16) ^ bxor));
            short8 k1 = *(const short8*)(kr + ((64 + g * 16) ^ bxor));
            f32x4 t0 = f32x4{0.f, 0.f, 0.f, 0.f};
            t0 = __builtin_amdgcn_mfma_f32_16x16x32_bf16(k0, bq0, t0, 0, 0, 0);
            t0 = __builtin_amdgcn_mfma_f32_16x16x32_bf16(k1, bq1, t0, 0, 0, 0);
            sa[sub] = t0;
        }
        __builtin_amdgcn_s_setprio(0);

        float pvv[16];
#pragma unroll
        for (int sub = 0; sub < 4; ++sub)
#pragma unroll
            for (int i = 0; i < 4; ++i) pvv[4 * sub + i] = sa[sub][i];
        if (st == qb) {   // diagonal tile
#pragma unroll
            for (int sub = 0; sub < 4; ++sub)
#pragma unroll
                for (int i = 0; i < 4; ++i)
                    if (S0 + 16 * sub + 4 * g + i > q0 + c) pvv[4 * sub + i] = -INFINITY;
        }
        float tmax = pvv[0];
#pragma unroll
        for (int j = 1; j < 16; ++j) tmax = fmaxf(tmax, pvv[j]);
        tmax = fmaxf(tmax, __shfl_xor(tmax, 16));
        tmax = fmaxf(tmax, __shfl_xor(tmax, 32));
        if (!__all(tmax - m_ <= 8.0f)) {   // defer-max
            float mn = fmaxf(m_, tmax);
            float fac = __expf(m_ - mn);
            m_ = mn;
            l_ *= fac;
#pragma unroll
            for (int i = 0; i < 4; ++i) {
                float fr = __shfl(fac, 4 * g + i);
#pragma unroll
                for (int nf = 0; nf < 4; ++nf) o[nf][i] *= fr;
            }
        }
        float pp[16], rs = 0.f;
#pragma unroll
        for (int j = 0; j < 16; ++j) { pp[j] = __expf(pvv[j] - m_); rs += pp[j]; }
        rs += __shfl_xor(rs, 16);
        rs += __shfl_xor(rs, 32);
        l_ += rs;

        // P -> bf16 (truncate), LDS transpose: row q=c gets s_local 16sub+4g+i
#pragma unroll
        for (int sub = 0; sub < 4; ++sub) {
            unsigned lo = (__float_as_uint(pp[4 * sub + 0]) >> 16) |
                          (__float_as_uint(pp[4 * sub + 1]) & 0xffff0000u);
            unsigned hi = (__float_as_uint(pp[4 * sub + 2]) >> 16) |
                          (__float_as_uint(pp[4 * sub + 3]) & 0xffff0000u);
            *(uint2*)(pw + 16 * sub + 4 * g) = make_uint2(lo, hi);
        }
        asm volatile("s_waitcnt lgkmcnt(0)" ::: "memory");
        short8 pa0 = *(const short8*)(&Plds[w][c * 72 + g * 8]);
        short8 pa1 = *(const short8*)(&Plds[w][c * 72 + 32 + g * 8]);

        __builtin_amdgcn_s_setprio(1);
#pragma unroll
        for (int nf = 0; nf < 4; ++nf) {
            const char* vr = (const char*)Vs + (nf * 16 + c) * 128;
            short8 v0 = *(const short8*)(vr + ((g * 16) ^ bxor));
            short8 v1 = *(const short8*)(vr + ((64 + g * 16) ^ bxor));
            o[nf] = __builtin_amdgcn_mfma_f32_16x16x32_bf16(pa0, v0, o[nf], 0, 0, 0);
            o[nf] = __builtin_amdgcn_mfma_f32_16x16x32_bf16(pa1, v1, o[nf], 0, 0, 0);
        }
        __builtin_amdgcn_s_setprio(0);

        __syncthreads();   // all LDS reads done before restage
        if (st < send) STAGE_KV(st + 1);
    }
#undef STAGE_KV

    if (qb < 8) {   // single chunk: finalize directly
#pragma unroll
        for (int i = 0; i < 4; ++i) {
            float rl = 1.0f / __shfl(l_, 4 * g + i);
            int tt = q0 + 4 * g + i;
#pragma unroll
            for (int nf = 0; nf < 4; ++nf)
                attout[((size_t)(bb * TSEQ + tt)) * CC + hh * DH + nf * 16 + c] =
                    f2bf(o[nf][i] * rl);
        }
    } else {
        const size_t slot = (size_t)(bh * 32 + qb) * 4 + sc;
        float* op = opart + slot * 4096;
#pragma unroll
        for (int nf = 0; nf < 4; ++nf)
#pragma unroll
            for (int i = 0; i < 4; ++i)
                op[(size_t)(w * 16 + 4 * g + i) * 64 + nf * 16 + c] = o[nf][i];
        if (g == 0) {
            mlpart[slot * 128 + w * 16 + c] = m_;
            mlpart[slot * 128 + 64 + w * 16 + c] = l_;
        }
    }
}

// ---------------------------------------------------------------------------
// Combine partials for qb >= 8.  grid (B*H, 24) -> qb = blockIdx.y + 8.
// ---------------------------------------------------------------------------
__global__ __launch_bounds__(256) void flash_combine(
    const float* __restrict__ opart, const float* __restrict__ mlpart,
    ushort_t* __restrict__ attout)
{
    const int bh = blockIdx.x, qb = blockIdx.y + 8;
    const int bb = bh >> 4, hh = bh & 15;
    const int nsc = (qb >> 3) + 1;      // 2..4
    const int t = threadIdx.x, r = t >> 2, qc = t & 3;
    const size_t slot0 = (size_t)(bh * 32 + qb) * 4;

    float mi[4], li[4];
    float M = -INFINITY;
#pragma unroll
    for (int i = 0; i < 4; ++i) {
        if (i < nsc) {
            mi[i] = mlpart[(slot0 + i) * 128 + r];
            li[i] = mlpart[(slot0 + i) * 128 + 64 + r];
            M = fmaxf(M, mi[i]);
        }
    }
    float L = 0.f;
    f32x4 acc[4];
#pragma unroll
    for (int j = 0; j < 4; ++j) acc[j] = f32x4{0.f, 0.f, 0.f, 0.f};
#pragma unroll
    for (int i = 0; i < 4; ++i) {
        if (i < nsc) {
            float F = __expf(mi[i] - M);
            L += li[i] * F;
            const f32x4* orow = (const f32x4*)(opart + (slot0 + i) * 4096 +
                                               (size_t)r * 64 + qc * 16);
#pragma unroll
            for (int j = 0; j < 4; ++j) acc[j] += orow[j] * F;
        }
    }
    float rl = 1.0f / L;
    unsigned wb[8];
#pragma unroll
    for (int j = 0; j < 4; ++j) {
        wb[2 * j] = (unsigned)f2bf(acc[j][0] * rl) | ((unsigned)f2bf(acc[j][1] * rl) << 16);
        wb[2 * j + 1] = (unsigned)f2bf(acc[j][2] * rl) | ((unsigned)f2bf(acc[j][3] * rl) << 16);
    }
    ushort_t* dst = attout + ((size_t)(bb * TSEQ + qb * 64 + r)) * CC + hh * DH + qc * 16;
    ((uint4*)dst)[0] = make_uint4(wb[0], wb[1], wb[2], wb[3]);
    ((uint4*)dst)[1] = make_uint4(wb[4], wb[5], wb[6], wb[7]);
}

// ---------------------------------------------------------------------------
extern "C" void kernel_launch(void* const* d_in, const int* in_sizes, int n_in,
                              void* d_out, int out_size, void* d_ws, size_t ws_size,
                              hipStream_t stream)
{
    (void)in_sizes; (void)n_in; (void)out_size; (void)ws_size;
    const float* x     = (const float*)d_in[0];
    const float* ln1_g = (const float*)d_in[1];
    const float* ln1_b = (const float*)d_in[2];
    const float* Wq    = (const float*)d_in[3];
    const float* Wk    = (const float*)d_in[4];
    const float* Wv    = (const float*)d_in[5];
    const float* Wo    = (const float*)d_in[6];
    const float* bo    = (const float*)d_in[7];
    const float* ln2_g = (const float*)d_in[8];
    const float* ln2_b = (const float*)d_in[9];
    const float* W1    = (const float*)d_in[10];
    const float* b1    = (const float*)d_in[11];
    const float* W2    = (const float*)d_in[12];
    const float* b2    = (const float*)d_in[13];

    char* p = (char*)d_ws;
    ushort_t* hbuf  = (ushort_t*)p;  p += (size_t)BT * CC * 2;
    ushort_t* WqkvT = (ushort_t*)p;  p += (size_t)3 * CC * CC * 2;
    ushort_t* WoT   = (ushort_t*)p;  p += (size_t)CC * CC * 2;
    ushort_t* W1T   = (ushort_t*)p;  p += (size_t)CC * HID * 2;
    ushort_t* W2T   = (ushort_t*)p;  p += (size_t)HID * CC * 2;
    ushort_t* Qb    = (ushort_t*)p;  p += (size_t)BT * CC * 2;
    ushort_t* Kbuf  = (ushort_t*)p;  p += (size_t)BT * CC * 2;
    ushort_t* Vt    = (ushort_t*)p;  p += (size_t)BT * CC * 2;
    ushort_t* atto  = (ushort_t*)p;  p += (size_t)BT * CC * 2;
    float*    x1    = (float*)p;     p += (size_t)BT * CC * 4;
    ushort_t* h2    = (ushort_t*)p;  p += (size_t)BT * CC * 2;
    ushort_t* mid   = (ushort_t*)p;  p += (size_t)BT * HID * 2;
    float*    opart = (float*)p;     p += (size_t)4096 * 4096 * 4;   // flash partials / FFN2 bf16 partials
    float*    mlprt = (float*)p;     p += (size_t)4096 * 128 * 4;

    dim3 blk(256);
    transpose_qkv<<<dim3(DH / 32, CC / 32, 3 * NH), blk, 0, stream>>>(Wq, Wk, Wv, WqkvT);
    transpose_cvt<<<dim3(CC / 32, CC / 32, 1), blk, 0, stream>>>(Wo, WoT, CC, CC);
    transpose_cvt<<<dim3(HID / 32, CC / 32, 1), blk, 0, stream>>>(W1, W1T, CC, HID);
    transpose_cvt<<<dim3(CC / 32, HID / 32, 1), blk, 0, stream>>>(W2, W2T, HID, CC);

    ln_kernel<<<dim3(BT), blk, 0, stream>>>(x, ln1_g, ln1_b, hbuf);
    gemm_tile<128, 128, 2, 2, 4, 4, 2, 2><<<dim3(BT / 128, 3072 / 128), blk, 0, stream>>>(
        hbuf, WqkvT, 3072, CC, CC, CC, nullptr, nullptr, Qb, Kbuf, Vt);
    flash_split<<<dim3(2 * NH, TSEQ / 64, 4), blk, 0, stream>>>(
        Qb, Kbuf, Vt, opart, mlprt, atto);
    flash_combine<<<dim3(2 * NH, TSEQ / 64 - 8), blk, 0, stream>>>(opart, mlprt, atto);
    gemm_tile<128, 64, 4, 1, 2, 4, 0, 3><<<dim3(BT / 128, CC / 64), blk, 0, stream>>>(
        atto, WoT, CC, CC, CC, CC, bo, x, (void*)x1, nullptr, nullptr);
    ln_kernel<<<dim3(BT), blk, 0, stream>>>(x1, ln2_g, ln2_b, h2);
    gemm_tile<128, 128, 2, 2, 4, 4, 1, 2><<<dim3(BT / 128, HID / 128), blk, 0, stream>>>(
        h2, W1T, HID, CC, CC, CC, b1, nullptr, (void*)mid, nullptr, nullptr);
    // FFN2 split-K: 2 chunks of K=2048 -> bf16 partials in opart (reused), D=3 ring
    gemm_tile<128, 64, 4, 1, 2, 4, 3, 3><<<dim3(BT / 128, CC / 64, 2), blk, 0, stream>>>(
        mid, W2T, CC, HID / 2, HID, HID, nullptr, nullptr, (void*)opart, nullptr, nullptr);
    ffn2_combine<<<dim3(BT * CC / 8 / 256), blk, 0, stream>>>(
        (const ushort_t*)opart, b2, x1, (float*)d_out);
}